// Round 4
// baseline (4834.653 us; speedup 1.0000x reference)
//
#include <hip/hip_runtime.h>
#include <math.h>

// ---------------------------------------------------------------------------
// DelayRNN persistent kernel, R4: fence-free grid barriers.
// R3 post-mortem: per-block __threadfence() in gridbar => buffer_wbl2+buffer_inv
// (full L2 writeback+invalidate) 320x per phase = the 14.7us/phase floor and
// the 99MB FETCH_SIZE. R4: all cross-block activations (h, av, gh, l1, o1, mem)
// use agent-scope relaxed atomics (sc1 -> coherent at L3, no L2 copies), so the
// steady-state barrier needs no cache maintenance: waitcnt + atomic add + spin.
// One fence-ful barrier after init flushes host-memset/init lines from L2s.
// Structure (roles, LDS layout) unchanged from R3.
// ---------------------------------------------------------------------------

#define kB 32
#define kT 128
#define kI 64
#define kH 256
#define kD 32
#define kC 64
#define kOut 32
#define kSteps (kT + kOut)            // 160
#define NB 160
#define NTHR 256
#define NT_ALL (NB * NTHR)            // 40960

// ws layout, float offsets
#define WS_H    64
#define WS_MEM  (WS_H + kB*kH)                  // h: [B][H]
#define WS_A    (WS_MEM + kB*kSteps*kI)         // mem events: [B][160][I]
#define WS_GH   (WS_A + kB*kH)                  // av: [B][H]
#define WS_L1   (WS_GH + kB*3*kH)               // gh: [B][3H]
#define WS_O1   (WS_L1 + kB*kD)                 // l1: [B][D]
#define WS_W2   (WS_O1 + kB*kH)                 // o1: [B][H]
#define WS_B2   (WS_W2 + kH*3*kH)               // W2 = W_e2@W_ih: [H][3H]
#define WS_G    (WS_B2 + 3*kH)                  // B2: [3H]
#define WS_END  (WS_G + kT*kB*kD)               // g_enc
#define WS_ZERO_BYTES ((size_t)WS_A * sizeof(float))  // zero bar+h+mem

// ---- coherent (L3-level) scalar access: agent-scope relaxed atomics ----
__device__ __forceinline__ float cload(const float* p) {
  return __hip_atomic_load(p, __ATOMIC_RELAXED, __HIP_MEMORY_SCOPE_AGENT);
}
__device__ __forceinline__ void cstore(float* p, float v) {
  __hip_atomic_store(p, v, __ATOMIC_RELAXED, __HIP_MEMORY_SCOPE_AGENT);
}

// ---- Threefry-2x32 ----
__device__ __forceinline__ void tf2x32(unsigned k0, unsigned k1,
                                       unsigned x0, unsigned x1,
                                       unsigned& o0, unsigned& o1) {
  unsigned ks2 = k0 ^ k1 ^ 0x1BD11BDAu;
  unsigned v0 = x0 + k0, v1 = x1 + k1;
#define TFR(r) { v0 += v1; v1 = (v1 << (r)) | (v1 >> (32-(r))); v1 ^= v0; }
  TFR(13) TFR(15) TFR(26) TFR(6)   v0 += k1;  v1 += ks2 + 1u;
  TFR(17) TFR(29) TFR(16) TFR(24)  v0 += ks2; v1 += k0  + 2u;
  TFR(13) TFR(15) TFR(26) TFR(6)   v0 += k0;  v1 += k1  + 3u;
  TFR(17) TFR(29) TFR(16) TFR(24)  v0 += k1;  v1 += ks2 + 4u;
  TFR(13) TFR(15) TFR(26) TFR(6)   v0 += ks2; v1 += k0  + 5u;
#undef TFR
  o0 = v0; o1 = v1;
}

__device__ __forceinline__ float bits_to_gumbel(unsigned bits) {
  float f = __uint_as_float((bits >> 9) | 0x3F800000u) - 1.0f;
  float u = f + 1.17549435e-38f;
  return -logf(-logf(u));
}

// Fence-ful barrier (used ONCE after init: flushes memset/init lines from L2s).
__device__ __forceinline__ void gridbar_full(unsigned* bar, unsigned target) {
  __syncthreads();
  if (threadIdx.x == 0) {
    __threadfence();
    __hip_atomic_fetch_add(bar, 1u, __ATOMIC_ACQ_REL, __HIP_MEMORY_SCOPE_AGENT);
    while (__hip_atomic_load(bar, __ATOMIC_RELAXED, __HIP_MEMORY_SCOPE_AGENT) < target)
      __builtin_amdgcn_s_sleep(1);
    __threadfence();
  }
  __syncthreads();
}

// Fence-free barrier: no L2 maintenance. Correct because all cross-block data
// ops are sc1 (agent-scope atomics) that complete at the coherence point.
__device__ __forceinline__ void gridbar_nf(unsigned* bar, unsigned target) {
  asm volatile("s_waitcnt vmcnt(0) lgkmcnt(0)" ::: "memory");  // per-wave drain
  __syncthreads();
  if (threadIdx.x == 0) {
    __hip_atomic_fetch_add(bar, 1u, __ATOMIC_RELAXED, __HIP_MEMORY_SCOPE_AGENT);
    while (__hip_atomic_load(bar, __ATOMIC_RELAXED, __HIP_MEMORY_SCOPE_AGENT) < target)
      __builtin_amdgcn_s_sleep(1);
    asm volatile("" ::: "memory");
  }
  __syncthreads();
}

__global__ __launch_bounds__(NTHR)
void delay_rnn(const float* __restrict__ x, const int* __restrict__ lengths,
               const float* __restrict__ W_dg1, const float* __restrict__ b_dg1,
               const float* __restrict__ W_dg2, const float* __restrict__ b_dg2,
               const float* __restrict__ W_e1,  const float* __restrict__ b_e1,
               const float* __restrict__ W_e2,  const float* __restrict__ b_e2,
               const float* __restrict__ W_ih,  const float* __restrict__ b_ih,
               const float* __restrict__ W_hh,  const float* __restrict__ b_hh,
               const float* __restrict__ W_f1,  const float* __restrict__ b_f1,
               const float* __restrict__ W_f2,  const float* __restrict__ b_f2,
               float* __restrict__ out, float* __restrict__ ws) {
  const int tid = threadIdx.x;
  const int bid = blockIdx.x;
  const int gid = bid * NTHR + tid;

  unsigned* bar = (unsigned*)ws;
  float* h   = ws + WS_H;
  float* mem = ws + WS_MEM;
  float* av  = ws + WS_A;
  float* gh  = ws + WS_GH;
  float* l1  = ws + WS_L1;
  float* o1  = ws + WS_O1;
  float* W2g = ws + WS_W2;
  float* B2g = ws + WS_B2;
  float* g   = ws + WS_G;

  // LDS carve. Strides padded to %32==4 floats for bank rotation.
  __shared__ float sA[kB * 260];       // stage: h / av / o1 [32][260]
  __shared__ float sB[2 * kB * 68];    // stage: x_t [32][68] + mem_t [32][68]
  __shared__ float w1[8 * 324];        // phase1 wt: GH 8x260 | E1 8x132 | DG1 8x324
  __shared__ float w1f[8 * 260];       // F1 weights
  __shared__ float w2[24 * 260];       // phase2 wt: GRU 24x260 | F2 8x260 | DG2 1024
  __shared__ float bias1[8], bias1f[8], bias2[24], bdg2s[kD], dec_s[kD];
  __shared__ float lg[kB][kD + 1];
  __shared__ int   sel[kB], len_s[kB];

  // ---------------- init: gumbel noise, W2 = W_e2@W_ih, B2 ----------------
  {
    unsigned k0, k1;
    tf2x32(0u, 42u, 0u, 0u, k0, k1);
    const int n = kT * kB * kD;
    for (int i = gid; i < n; i += NT_ALL) {
      unsigned a, b;
      tf2x32(k0, k1, 0u, (unsigned)i, a, b);
      g[i] = bits_to_gumbel(a ^ b);
    }
  }
  for (int idx = gid; idx < kH * 3 * kH; idx += NT_ALL) {
    int k = idx / (3 * kH), n = idx % (3 * kH);
    const float* wr = W_e2 + k * kH;
    float s0 = 0, s1 = 0, s2 = 0, s3 = 0;
    for (int m = 0; m < kH; m += 4) {
      float4 wv = *(const float4*)(wr + m);
      s0 += wv.x * W_ih[(m    ) * 3 * kH + n];
      s1 += wv.y * W_ih[(m + 1) * 3 * kH + n];
      s2 += wv.z * W_ih[(m + 2) * 3 * kH + n];
      s3 += wv.w * W_ih[(m + 3) * 3 * kH + n];
    }
    W2g[idx] = ((s0 + s1) + (s2 + s3));
  }
  for (int n = gid; n < 3 * kH; n += NT_ALL) {
    float s = b_ih[n];
    for (int m = 0; m < kH; ++m) s += b_e2[m] * W_ih[m * 3 * kH + n];
    B2g[n] = s;
  }

  unsigned round = 1;
  gridbar_full(bar, NB * round); round++;   // flush init + memset lines from L2s

  // ---------------- stage persistent weight slices into LDS ----------------
  if (bid < 96) {                                      // GH
    const int jb = bid * 8;
    for (int i = tid; i < 2048; i += NTHR) {
      int jj = i >> 8, k = i & 255;
      w1[jj * 260 + k] = W_hh[k * 768 + jb + jj];
    }
    if (tid < 8) bias1[tid] = b_hh[jb + tid];
    if (bid < 32) {                                    // + GRU
      const int jb2 = bid * 8;
      for (int i = tid; i < 6144; i += NTHR) {
        int gg = i >> 11, r = i & 2047, jj = r >> 8, k = r & 255;
        w2[(gg * 8 + jj) * 260 + k] = W2g[k * 768 + gg * kH + jb2 + jj];
      }
      if (tid < 24) { int gg = tid / 8, jj = tid % 8; bias2[tid] = B2g[gg * kH + jb2 + jj]; }
      if (tid < kB) len_s[tid] = lengths[tid];
    }
  } else if (bid < 128) {                              // E1
    const int jb = (bid - 96) * 8;
    for (int i = tid; i < 1024; i += NTHR) {
      int jj = i >> 7, k = i & 127;
      w1[jj * 132 + k] = W_e1[k * kH + jb + jj];
    }
    if (tid < 8) bias1[tid] = b_e1[jb + tid];
    if (bid < 104) {                                   // + F2
      const int cb = (bid - 96) * 8;
      for (int i = tid; i < 2048; i += NTHR) {
        int cc = i >> 8, k = i & 255;
        w2[cc * 260 + k] = W_f2[k * kC + cb + cc];
      }
      if (tid < 8) bias2[tid] = b_f2[cb + tid];
    }
  } else {                                             // DG1 / F1
    const int q = bid - 128, jb = q * 8;
    if (q < 4) {
      for (int i = tid; i < 2560; i += NTHR) {
        int jj = i / 320, k = i % 320;
        w1[jj * 324 + k] = W_dg1[k * kD + jb + jj];
      }
      if (tid < 8) bias1[tid] = b_dg1[jb + tid];
    }
    for (int i = tid; i < 2048; i += NTHR) {
      int jj = i >> 8, k = i & 255;
      w1f[jj * 260 + k] = W_f1[k * kH + jb + jj];
    }
    if (tid < 8) bias1f[tid] = b_f1[jb + tid];
    if (q == 0) {                                      // + DG2/scatter
      for (int i = tid; i < kD * kD; i += NTHR) w2[i] = W_dg2[i];
      if (tid < kD) { bdg2s[tid] = b_dg2[tid]; dec_s[tid] = powf(0.99f, (float)(tid + 1)); }
    }
  }
  __syncthreads();

  const float4* sA4  = (const float4*)sA;
  const float4* sB4  = (const float4*)sB;
  const float4* w14  = (const float4*)w1;
  const float4* w1f4 = (const float4*)w1f;
  const float4* w24  = (const float4*)w2;

  // ---------------- time loop ----------------
  for (int s = 0; s <= kSteps; ++s) {
    const bool enc  = (s < kT);
    const bool rnn  = (s < kSteps);
    const bool head = (s > kT);

    // ================= PHASE 1 =================
    if (bid < 96) {
      if (rnn) {  // gh = h @ W_hh + b_hh
        #pragma unroll 8
        for (int i = tid; i < kB * kH; i += NTHR)
          sA[(i >> 8) * 260 + (i & 255)] = cload(&h[i]);
        __syncthreads();
        const int b = tid >> 3, jj = tid & 7;
        float a0 = 0, a1 = 0, a2 = 0, a3 = 0;
        for (int k4 = 0; k4 < 64; ++k4) {
          float4 h4 = sA4[b * 65 + k4];
          float4 w4 = w14[jj * 65 + k4];
          a0 += h4.x * w4.x; a1 += h4.y * w4.y; a2 += h4.z * w4.z; a3 += h4.w * w4.w;
        }
        cstore(&gh[b * 768 + bid * 8 + jj], ((a0 + a1) + (a2 + a3)) + bias1[jj]);
      }
    } else if (bid < 128) {
      if (rnn) {  // av = elu([x_t, mem_t] @ W_e1 + b_e1)
        #pragma unroll 8
        for (int i = tid; i < kB * kI; i += NTHR) {
          int b = i >> 6, k = i & 63;
          sB[b * 68 + k] = enc ? x[(b * kT + s) * kI + k] : 0.f;
          sB[2176 + b * 68 + k] = cload(&mem[(b * kSteps + s) * kI + k]);
        }
        __syncthreads();
        const int b = tid >> 3, jj = tid & 7;
        float a0 = 0, a1 = 0, a2 = 0, a3 = 0;
        for (int k4 = 0; k4 < 16; ++k4) {
          float4 x4 = sB4[b * 17 + k4];
          float4 w4 = w14[jj * 33 + k4];
          a0 += x4.x * w4.x; a1 += x4.y * w4.y; a2 += x4.z * w4.z; a3 += x4.w * w4.w;
        }
        for (int k4 = 0; k4 < 16; ++k4) {
          float4 m4 = sB4[544 + b * 17 + k4];
          float4 w4 = w14[jj * 33 + 16 + k4];
          a0 += m4.x * w4.x; a1 += m4.y * w4.y; a2 += m4.z * w4.z; a3 += m4.w * w4.w;
        }
        float v = ((a0 + a1) + (a2 + a3)) + bias1[jj];
        cstore(&av[b * kH + (bid - 96) * 8 + jj], v > 0.f ? v : expm1f(v));
      }
    } else {
      const int q = bid - 128;
      if (enc && q < 4) {  // l1 = elu([x_t, h] @ W_dg1 + b_dg1)
        #pragma unroll 8
        for (int i = tid; i < kB * kH; i += NTHR)
          sA[(i >> 8) * 260 + (i & 255)] = cload(&h[i]);
        for (int i = tid; i < kB * kI; i += NTHR) {
          int b = i >> 6, k = i & 63;
          sB[b * 68 + k] = x[(b * kT + s) * kI + k];
        }
        __syncthreads();
        const int b = tid >> 3, jj = tid & 7;
        float a0 = 0, a1 = 0, a2 = 0, a3 = 0;
        for (int k4 = 0; k4 < 16; ++k4) {
          float4 x4 = sB4[b * 17 + k4];
          float4 w4 = w14[jj * 81 + k4];
          a0 += x4.x * w4.x; a1 += x4.y * w4.y; a2 += x4.z * w4.z; a3 += x4.w * w4.w;
        }
        for (int k4 = 0; k4 < 64; ++k4) {
          float4 h4 = sA4[b * 65 + k4];
          float4 w4 = w14[jj * 81 + 16 + k4];
          a0 += h4.x * w4.x; a1 += h4.y * w4.y; a2 += h4.z * w4.z; a3 += h4.w * w4.w;
        }
        float v = ((a0 + a1) + (a2 + a3)) + bias1[jj];
        cstore(&l1[b * kD + q * 8 + jj], v > 0.f ? v : expm1f(v));
      } else if (head) {  // o1 = relu(h @ W_f1 + b_f1)
        #pragma unroll 8
        for (int i = tid; i < kB * kH; i += NTHR)
          sA[(i >> 8) * 260 + (i & 255)] = cload(&h[i]);
        __syncthreads();
        const int b = tid >> 3, jj = tid & 7;
        float a0 = 0, a1 = 0, a2 = 0, a3 = 0;
        for (int k4 = 0; k4 < 64; ++k4) {
          float4 h4 = sA4[b * 65 + k4];
          float4 w4 = w1f4[jj * 65 + k4];
          a0 += h4.x * w4.x; a1 += h4.y * w4.y; a2 += h4.z * w4.z; a3 += h4.w * w4.w;
        }
        float v = ((a0 + a1) + (a2 + a3)) + bias1f[jj];
        cstore(&o1[b * kH + q * 8 + jj], v > 0.f ? v : 0.f);
      }
    }
    gridbar_nf(bar, NB * round); round++;

    // ================= PHASE 2 =================
    if (bid < 32) {
      if (rnn) {  // GRU update
        #pragma unroll 8
        for (int i = tid; i < kB * kH; i += NTHR)
          sA[(i >> 8) * 260 + (i & 255)] = cload(&av[i]);
        __syncthreads();
        const int b = tid >> 3, jj = tid & 7;
        const int j = bid * 8 + jj;
        float r0 = 0, r1 = 0, z0 = 0, z1 = 0, n0 = 0, n1 = 0;
        for (int k4 = 0; k4 < 64; ++k4) {
          float4 a4 = sA4[b * 65 + k4];
          float4 wr = w24[(jj     ) * 65 + k4];
          float4 wz = w24[(8  + jj) * 65 + k4];
          float4 wn = w24[(16 + jj) * 65 + k4];
          r0 += a4.x * wr.x + a4.y * wr.y; r1 += a4.z * wr.z + a4.w * wr.w;
          z0 += a4.x * wz.x + a4.y * wz.y; z1 += a4.z * wz.z + a4.w * wz.w;
          n0 += a4.x * wn.x + a4.y * wn.y; n1 += a4.z * wn.z + a4.w * wn.w;
        }
        const float* ghb = gh + b * 768 + j;
        float ir  = (r0 + r1) + bias2[jj]      + cload(&ghb[0]);
        float iz  = (z0 + z1) + bias2[8 + jj]  + cload(&ghb[kH]);
        float hn  = cload(&ghb[2 * kH]);
        float in_ = (n0 + n1) + bias2[16 + jj];
        float r = 1.f / (1.f + expf(-ir));
        float z = 1.f / (1.f + expf(-iz));
        float n = tanhf(in_ + r * hn);
        float hold = cload(&h[b * kH + j]);
        float nh = (1.f - z) * n + z * hold;
        cstore(&h[b * kH + j], enc ? ((s < len_s[b]) ? nh : hold) : nh);
      }
      __syncthreads();  // protect sA reuse before next phase-1 staging
    } else if (bid >= 96 && bid < 104) {
      if (head) {  // out = o1 @ W_f2 + b_f2
        #pragma unroll 8
        for (int i = tid; i < kB * kH; i += NTHR)
          sA[(i >> 8) * 260 + (i & 255)] = cload(&o1[i]);
        __syncthreads();
        const int b = tid >> 3, cc = tid & 7;
        float a0 = 0, a1 = 0, a2 = 0, a3 = 0;
        for (int k4 = 0; k4 < 64; ++k4) {
          float4 o4 = sA4[b * 65 + k4];
          float4 w4 = w24[cc * 65 + k4];
          a0 += o4.x * w4.x; a1 += o4.y * w4.y; a2 += o4.z * w4.z; a3 += o4.w * w4.w;
        }
        out[(b * kOut + (s - 1 - kT)) * kC + (bid - 96) * 8 + cc] =
            ((a0 + a1) + (a2 + a3)) + bias2[cc];
      }
      __syncthreads();
    } else if (bid == 128) {
      if (enc) {  // dg2 + gumbel argmax + event scatter
        for (int i = tid; i < kB * kD; i += NTHR) {
          int b = i >> 5, j = i & 31;
          float sv = bdg2s[j];
          for (int k = 0; k < kD; ++k) sv += cload(&l1[b * kD + k]) * w2[k * kD + j];
          lg[b][j] = sv + g[(s * kB + b) * kD + j];
        }
        __syncthreads();
        if (tid < kB) {
          float best = lg[tid][0]; int bi = 0;
          for (int j = 1; j < kD; ++j) { float v = lg[tid][j]; if (v > best) { best = v; bi = j; } }
          sel[tid] = bi;
        }
        __syncthreads();
        for (int i = tid; i < kB * kI; i += NTHR) {
          int b = i >> 6, ii = i & 63;
          int d = sel[b];
          int c = s + 1 + d;
          int e = -1;
          if (c < kT) e = c;
          else { int rr = c - kT - 1;
                 if (rr >= 0 && (rr & 1) == 0) { int kk = rr >> 1; if (kk < kOut) e = kT + kk; } }
          if (e >= 0) {
            float* p = &mem[(b * kSteps + e) * kI + ii];
            cstore(p, cload(p) + x[(b * kT + s) * kI + ii] * dec_s[d]);
          }
        }
      }
    }
    gridbar_nf(bar, NB * round); round++;
  }
}

extern "C" void kernel_launch(void* const* d_in, const int* in_sizes, int n_in,
                              void* d_out, int out_size, void* d_ws, size_t ws_size,
                              hipStream_t stream) {
  (void)in_sizes; (void)n_in; (void)out_size; (void)ws_size;
  const float* x      = (const float*)d_in[0];
  const int*   lens   = (const int*)  d_in[1];
  const float* W_dg1  = (const float*)d_in[3];
  const float* b_dg1  = (const float*)d_in[4];
  const float* W_dg2  = (const float*)d_in[5];
  const float* b_dg2  = (const float*)d_in[6];
  const float* W_e1   = (const float*)d_in[7];
  const float* b_e1   = (const float*)d_in[8];
  const float* W_e2   = (const float*)d_in[9];
  const float* b_e2   = (const float*)d_in[10];
  const float* W_ih   = (const float*)d_in[11];
  const float* b_ih   = (const float*)d_in[12];
  const float* W_hh   = (const float*)d_in[13];
  const float* b_hh   = (const float*)d_in[14];
  const float* W_f1   = (const float*)d_in[15];
  const float* b_f1   = (const float*)d_in[16];
  const float* W_f2   = (const float*)d_in[17];
  const float* b_f2   = (const float*)d_in[18];

  hipMemsetAsync(d_ws, 0, WS_ZERO_BYTES, stream);
  delay_rnn<<<dim3(NB), dim3(NTHR), 0, stream>>>(
      x, lens, W_dg1, b_dg1, W_dg2, b_dg2, W_e1, b_e1, W_e2, b_e2,
      W_ih, b_ih, W_hh, b_hh, W_f1, b_f1, W_f2, b_f2,
      (float*)d_out, (float*)d_ws);
}

// Round 5
// 4188.128 us; speedup vs baseline: 1.1544x; 1.1544x over previous
//
#include <hip/hip_runtime.h>
#include <math.h>

// ---------------------------------------------------------------------------
// DelayRNN persistent kernel, R5: tree-arrival + epoch-broadcast grid barrier.
// R4 post-mortem: fence removal was NEUTRAL => the ~10us/barrier comes from
// 160 RMWs on ONE line contending with 160 spinners polling that same line.
// R5: 8 group counters (arrival RMWs spread across lines) -> root counter ->
// single epoch flag store; spinners poll ONLY the epoch line (no RMW traffic).
// Everything else identical to R4 (sc1 activation protocol, roles, LDS).
// ---------------------------------------------------------------------------

#define kB 32
#define kT 128
#define kI 64
#define kH 256
#define kD 32
#define kC 64
#define kOut 32
#define kSteps (kT + kOut)            // 160
#define NB 160
#define NTHR 256
#define NT_ALL (NB * NTHR)            // 40960
#define BPG 20                        // blocks per barrier group (160/8)
#define NGRP 8

// ws layout, float offsets. Barrier area: u[0..255] = 8 group ctrs (stride 32
// uints = 128B), u[256] root, u[288] epoch, u[320] init-barrier ctr.
#define WS_H    384
#define WS_MEM  (WS_H + kB*kH)                  // h: [B][H]
#define WS_A    (WS_MEM + kB*kSteps*kI)         // mem events: [B][160][I]
#define WS_GH   (WS_A + kB*kH)                  // av: [B][H]
#define WS_L1   (WS_GH + kB*3*kH)               // gh: [B][3H]
#define WS_O1   (WS_L1 + kB*kD)                 // l1: [B][D]
#define WS_W2   (WS_O1 + kB*kH)                 // o1: [B][H]
#define WS_B2   (WS_W2 + kH*3*kH)               // W2 = W_e2@W_ih: [H][3H]
#define WS_G    (WS_B2 + 3*kH)                  // B2: [3H]
#define WS_END  (WS_G + kT*kB*kD)               // g_enc
#define WS_ZERO_BYTES ((size_t)WS_A * sizeof(float))  // zero bar+h+mem

// ---- coherent (L3-level) scalar access: agent-scope relaxed atomics ----
__device__ __forceinline__ float cload(const float* p) {
  return __hip_atomic_load(p, __ATOMIC_RELAXED, __HIP_MEMORY_SCOPE_AGENT);
}
__device__ __forceinline__ void cstore(float* p, float v) {
  __hip_atomic_store(p, v, __ATOMIC_RELAXED, __HIP_MEMORY_SCOPE_AGENT);
}

// ---- Threefry-2x32 ----
__device__ __forceinline__ void tf2x32(unsigned k0, unsigned k1,
                                       unsigned x0, unsigned x1,
                                       unsigned& o0, unsigned& o1) {
  unsigned ks2 = k0 ^ k1 ^ 0x1BD11BDAu;
  unsigned v0 = x0 + k0, v1 = x1 + k1;
#define TFR(r) { v0 += v1; v1 = (v1 << (r)) | (v1 >> (32-(r))); v1 ^= v0; }
  TFR(13) TFR(15) TFR(26) TFR(6)   v0 += k1;  v1 += ks2 + 1u;
  TFR(17) TFR(29) TFR(16) TFR(24)  v0 += ks2; v1 += k0  + 2u;
  TFR(13) TFR(15) TFR(26) TFR(6)   v0 += k0;  v1 += k1  + 3u;
  TFR(17) TFR(29) TFR(16) TFR(24)  v0 += k1;  v1 += ks2 + 4u;
  TFR(13) TFR(15) TFR(26) TFR(6)   v0 += ks2; v1 += k0  + 5u;
#undef TFR
  o0 = v0; o1 = v1;
}

__device__ __forceinline__ float bits_to_gumbel(unsigned bits) {
  float f = __uint_as_float((bits >> 9) | 0x3F800000u) - 1.0f;
  float u = f + 1.17549435e-38f;
  return -logf(-logf(u));
}

// Fence-ful flat barrier (used ONCE after init; cost irrelevant).
__device__ __forceinline__ void gridbar_full(unsigned* u, unsigned target) {
  __syncthreads();
  if (threadIdx.x == 0) {
    __threadfence();
    __hip_atomic_fetch_add(&u[320], 1u, __ATOMIC_ACQ_REL, __HIP_MEMORY_SCOPE_AGENT);
    while (__hip_atomic_load(&u[320], __ATOMIC_RELAXED, __HIP_MEMORY_SCOPE_AGENT) < target)
      __builtin_amdgcn_s_sleep(1);
    __threadfence();
  }
  __syncthreads();
}

// Fence-free tree barrier. Arrival: group ctr RMW (8 lines in parallel);
// last-in-group bumps root; last-at-root stores epoch. Detection: poll epoch
// only (read-only line). Monotonic counters — no reset races.
__device__ __forceinline__ void gridbar_nf(unsigned* u, unsigned nround, int grp) {
  asm volatile("s_waitcnt vmcnt(0) lgkmcnt(0)" ::: "memory");  // drain sc1 stores
  __syncthreads();
  if (threadIdx.x == 0) {
    unsigned old = __hip_atomic_fetch_add(&u[grp * 32], 1u,
                      __ATOMIC_RELAXED, __HIP_MEMORY_SCOPE_AGENT);
    if (old + 1u == BPG * nround) {               // last in group this round
      unsigned r = __hip_atomic_fetch_add(&u[256], 1u,
                      __ATOMIC_RELAXED, __HIP_MEMORY_SCOPE_AGENT);
      if (r + 1u == NGRP * nround)                // globally last
        __hip_atomic_store(&u[288], nround, __ATOMIC_RELAXED, __HIP_MEMORY_SCOPE_AGENT);
    }
    while (__hip_atomic_load(&u[288], __ATOMIC_RELAXED, __HIP_MEMORY_SCOPE_AGENT) < nround)
      __builtin_amdgcn_s_sleep(2);
    asm volatile("" ::: "memory");
  }
  __syncthreads();
}

__global__ __launch_bounds__(NTHR)
void delay_rnn(const float* __restrict__ x, const int* __restrict__ lengths,
               const float* __restrict__ W_dg1, const float* __restrict__ b_dg1,
               const float* __restrict__ W_dg2, const float* __restrict__ b_dg2,
               const float* __restrict__ W_e1,  const float* __restrict__ b_e1,
               const float* __restrict__ W_e2,  const float* __restrict__ b_e2,
               const float* __restrict__ W_ih,  const float* __restrict__ b_ih,
               const float* __restrict__ W_hh,  const float* __restrict__ b_hh,
               const float* __restrict__ W_f1,  const float* __restrict__ b_f1,
               const float* __restrict__ W_f2,  const float* __restrict__ b_f2,
               float* __restrict__ out, float* __restrict__ ws) {
  const int tid = threadIdx.x;
  const int bid = blockIdx.x;
  const int gid = bid * NTHR + tid;
  const int grp = bid / BPG;

  unsigned* baru = (unsigned*)ws;
  float* h   = ws + WS_H;
  float* mem = ws + WS_MEM;
  float* av  = ws + WS_A;
  float* gh  = ws + WS_GH;
  float* l1  = ws + WS_L1;
  float* o1  = ws + WS_O1;
  float* W2g = ws + WS_W2;
  float* B2g = ws + WS_B2;
  float* g   = ws + WS_G;

  // LDS carve. Strides padded to %32==4 floats for bank rotation.
  __shared__ float sA[kB * 260];       // stage: h / av / o1 [32][260]
  __shared__ float sB[2 * kB * 68];    // stage: x_t [32][68] + mem_t [32][68]
  __shared__ float w1[8 * 324];        // phase1 wt: GH 8x260 | E1 8x132 | DG1 8x324
  __shared__ float w1f[8 * 260];       // F1 weights
  __shared__ float w2[24 * 260];       // phase2 wt: GRU 24x260 | F2 8x260 | DG2 1024
  __shared__ float bias1[8], bias1f[8], bias2[24], bdg2s[kD], dec_s[kD];
  __shared__ float lg[kB][kD + 1];
  __shared__ int   sel[kB], len_s[kB];

  // ---------------- init: gumbel noise, W2 = W_e2@W_ih, B2 ----------------
  {
    unsigned k0, k1;
    tf2x32(0u, 42u, 0u, 0u, k0, k1);
    const int n = kT * kB * kD;
    for (int i = gid; i < n; i += NT_ALL) {
      unsigned a, b;
      tf2x32(k0, k1, 0u, (unsigned)i, a, b);
      g[i] = bits_to_gumbel(a ^ b);
    }
  }
  for (int idx = gid; idx < kH * 3 * kH; idx += NT_ALL) {
    int k = idx / (3 * kH), n = idx % (3 * kH);
    const float* wr = W_e2 + k * kH;
    float s0 = 0, s1 = 0, s2 = 0, s3 = 0;
    for (int m = 0; m < kH; m += 4) {
      float4 wv = *(const float4*)(wr + m);
      s0 += wv.x * W_ih[(m    ) * 3 * kH + n];
      s1 += wv.y * W_ih[(m + 1) * 3 * kH + n];
      s2 += wv.z * W_ih[(m + 2) * 3 * kH + n];
      s3 += wv.w * W_ih[(m + 3) * 3 * kH + n];
    }
    W2g[idx] = ((s0 + s1) + (s2 + s3));
  }
  for (int n = gid; n < 3 * kH; n += NT_ALL) {
    float s = b_ih[n];
    for (int m = 0; m < kH; ++m) s += b_e2[m] * W_ih[m * 3 * kH + n];
    B2g[n] = s;
  }

  gridbar_full(baru, NB);   // once: flush init + memset lines from L2s

  // ---------------- stage persistent weight slices into LDS ----------------
  if (bid < 96) {                                      // GH
    const int jb = bid * 8;
    for (int i = tid; i < 2048; i += NTHR) {
      int jj = i >> 8, k = i & 255;
      w1[jj * 260 + k] = W_hh[k * 768 + jb + jj];
    }
    if (tid < 8) bias1[tid] = b_hh[jb + tid];
    if (bid < 32) {                                    // + GRU
      const int jb2 = bid * 8;
      for (int i = tid; i < 6144; i += NTHR) {
        int gg = i >> 11, r = i & 2047, jj = r >> 8, k = r & 255;
        w2[(gg * 8 + jj) * 260 + k] = W2g[k * 768 + gg * kH + jb2 + jj];
      }
      if (tid < 24) { int gg = tid / 8, jj = tid % 8; bias2[tid] = B2g[gg * kH + jb2 + jj]; }
      if (tid < kB) len_s[tid] = lengths[tid];
    }
  } else if (bid < 128) {                              // E1
    const int jb = (bid - 96) * 8;
    for (int i = tid; i < 1024; i += NTHR) {
      int jj = i >> 7, k = i & 127;
      w1[jj * 132 + k] = W_e1[k * kH + jb + jj];
    }
    if (tid < 8) bias1[tid] = b_e1[jb + tid];
    if (bid < 104) {                                   // + F2
      const int cb = (bid - 96) * 8;
      for (int i = tid; i < 2048; i += NTHR) {
        int cc = i >> 8, k = i & 255;
        w2[cc * 260 + k] = W_f2[k * kC + cb + cc];
      }
      if (tid < 8) bias2[tid] = b_f2[cb + tid];
    }
  } else {                                             // DG1 / F1
    const int q = bid - 128, jb = q * 8;
    if (q < 4) {
      for (int i = tid; i < 2560; i += NTHR) {
        int jj = i / 320, k = i % 320;
        w1[jj * 324 + k] = W_dg1[k * kD + jb + jj];
      }
      if (tid < 8) bias1[tid] = b_dg1[jb + tid];
    }
    for (int i = tid; i < 2048; i += NTHR) {
      int jj = i >> 8, k = i & 255;
      w1f[jj * 260 + k] = W_f1[k * kH + jb + jj];
    }
    if (tid < 8) bias1f[tid] = b_f1[jb + tid];
    if (q == 0) {                                      // + DG2/scatter
      for (int i = tid; i < kD * kD; i += NTHR) w2[i] = W_dg2[i];
      if (tid < kD) { bdg2s[tid] = b_dg2[tid]; dec_s[tid] = powf(0.99f, (float)(tid + 1)); }
    }
  }
  __syncthreads();

  const float4* sA4  = (const float4*)sA;
  const float4* sB4  = (const float4*)sB;
  const float4* w14  = (const float4*)w1;
  const float4* w1f4 = (const float4*)w1f;
  const float4* w24  = (const float4*)w2;

  unsigned nr = 1;   // tree-barrier round counter

  // ---------------- time loop ----------------
  for (int s = 0; s <= kSteps; ++s) {
    const bool enc  = (s < kT);
    const bool rnn  = (s < kSteps);
    const bool head = (s > kT);

    // ================= PHASE 1 =================
    if (bid < 96) {
      if (rnn) {  // gh = h @ W_hh + b_hh
        #pragma unroll 8
        for (int i = tid; i < kB * kH; i += NTHR)
          sA[(i >> 8) * 260 + (i & 255)] = cload(&h[i]);
        __syncthreads();
        const int b = tid >> 3, jj = tid & 7;
        float a0 = 0, a1 = 0, a2 = 0, a3 = 0;
        for (int k4 = 0; k4 < 64; ++k4) {
          float4 h4 = sA4[b * 65 + k4];
          float4 w4 = w14[jj * 65 + k4];
          a0 += h4.x * w4.x; a1 += h4.y * w4.y; a2 += h4.z * w4.z; a3 += h4.w * w4.w;
        }
        cstore(&gh[b * 768 + bid * 8 + jj], ((a0 + a1) + (a2 + a3)) + bias1[jj]);
      }
    } else if (bid < 128) {
      if (rnn) {  // av = elu([x_t, mem_t] @ W_e1 + b_e1)
        #pragma unroll 8
        for (int i = tid; i < kB * kI; i += NTHR) {
          int b = i >> 6, k = i & 63;
          sB[b * 68 + k] = enc ? x[(b * kT + s) * kI + k] : 0.f;
          sB[2176 + b * 68 + k] = cload(&mem[(b * kSteps + s) * kI + k]);
        }
        __syncthreads();
        const int b = tid >> 3, jj = tid & 7;
        float a0 = 0, a1 = 0, a2 = 0, a3 = 0;
        for (int k4 = 0; k4 < 16; ++k4) {
          float4 x4 = sB4[b * 17 + k4];
          float4 w4 = w14[jj * 33 + k4];
          a0 += x4.x * w4.x; a1 += x4.y * w4.y; a2 += x4.z * w4.z; a3 += x4.w * w4.w;
        }
        for (int k4 = 0; k4 < 16; ++k4) {
          float4 m4 = sB4[544 + b * 17 + k4];
          float4 w4 = w14[jj * 33 + 16 + k4];
          a0 += m4.x * w4.x; a1 += m4.y * w4.y; a2 += m4.z * w4.z; a3 += m4.w * w4.w;
        }
        float v = ((a0 + a1) + (a2 + a3)) + bias1[jj];
        cstore(&av[b * kH + (bid - 96) * 8 + jj], v > 0.f ? v : expm1f(v));
      }
    } else {
      const int q = bid - 128;
      if (enc && q < 4) {  // l1 = elu([x_t, h] @ W_dg1 + b_dg1)
        #pragma unroll 8
        for (int i = tid; i < kB * kH; i += NTHR)
          sA[(i >> 8) * 260 + (i & 255)] = cload(&h[i]);
        for (int i = tid; i < kB * kI; i += NTHR) {
          int b = i >> 6, k = i & 63;
          sB[b * 68 + k] = x[(b * kT + s) * kI + k];
        }
        __syncthreads();
        const int b = tid >> 3, jj = tid & 7;
        float a0 = 0, a1 = 0, a2 = 0, a3 = 0;
        for (int k4 = 0; k4 < 16; ++k4) {
          float4 x4 = sB4[b * 17 + k4];
          float4 w4 = w14[jj * 81 + k4];
          a0 += x4.x * w4.x; a1 += x4.y * w4.y; a2 += x4.z * w4.z; a3 += x4.w * w4.w;
        }
        for (int k4 = 0; k4 < 64; ++k4) {
          float4 h4 = sA4[b * 65 + k4];
          float4 w4 = w14[jj * 81 + 16 + k4];
          a0 += h4.x * w4.x; a1 += h4.y * w4.y; a2 += h4.z * w4.z; a3 += h4.w * w4.w;
        }
        float v = ((a0 + a1) + (a2 + a3)) + bias1[jj];
        cstore(&l1[b * kD + q * 8 + jj], v > 0.f ? v : expm1f(v));
      } else if (head) {  // o1 = relu(h @ W_f1 + b_f1)
        #pragma unroll 8
        for (int i = tid; i < kB * kH; i += NTHR)
          sA[(i >> 8) * 260 + (i & 255)] = cload(&h[i]);
        __syncthreads();
        const int b = tid >> 3, jj = tid & 7;
        float a0 = 0, a1 = 0, a2 = 0, a3 = 0;
        for (int k4 = 0; k4 < 64; ++k4) {
          float4 h4 = sA4[b * 65 + k4];
          float4 w4 = w1f4[jj * 65 + k4];
          a0 += h4.x * w4.x; a1 += h4.y * w4.y; a2 += h4.z * w4.z; a3 += h4.w * w4.w;
        }
        float v = ((a0 + a1) + (a2 + a3)) + bias1f[jj];
        cstore(&o1[b * kH + q * 8 + jj], v > 0.f ? v : 0.f);
      }
    }
    gridbar_nf(baru, nr, grp); nr++;

    // ================= PHASE 2 =================
    if (bid < 32) {
      if (rnn) {  // GRU update
        #pragma unroll 8
        for (int i = tid; i < kB * kH; i += NTHR)
          sA[(i >> 8) * 260 + (i & 255)] = cload(&av[i]);
        __syncthreads();
        const int b = tid >> 3, jj = tid & 7;
        const int j = bid * 8 + jj;
        float r0 = 0, r1 = 0, z0 = 0, z1 = 0, n0 = 0, n1 = 0;
        for (int k4 = 0; k4 < 64; ++k4) {
          float4 a4 = sA4[b * 65 + k4];
          float4 wr = w24[(jj     ) * 65 + k4];
          float4 wz = w24[(8  + jj) * 65 + k4];
          float4 wn = w24[(16 + jj) * 65 + k4];
          r0 += a4.x * wr.x + a4.y * wr.y; r1 += a4.z * wr.z + a4.w * wr.w;
          z0 += a4.x * wz.x + a4.y * wz.y; z1 += a4.z * wz.z + a4.w * wz.w;
          n0 += a4.x * wn.x + a4.y * wn.y; n1 += a4.z * wn.z + a4.w * wn.w;
        }
        const float* ghb = gh + b * 768 + j;
        float ir  = (r0 + r1) + bias2[jj]      + cload(&ghb[0]);
        float iz  = (z0 + z1) + bias2[8 + jj]  + cload(&ghb[kH]);
        float hn  = cload(&ghb[2 * kH]);
        float in_ = (n0 + n1) + bias2[16 + jj];
        float r = 1.f / (1.f + expf(-ir));
        float z = 1.f / (1.f + expf(-iz));
        float n = tanhf(in_ + r * hn);
        float hold = cload(&h[b * kH + j]);
        float nh = (1.f - z) * n + z * hold;
        cstore(&h[b * kH + j], enc ? ((s < len_s[b]) ? nh : hold) : nh);
      }
      __syncthreads();  // protect sA reuse before next phase-1 staging
    } else if (bid >= 96 && bid < 104) {
      if (head) {  // out = o1 @ W_f2 + b_f2
        #pragma unroll 8
        for (int i = tid; i < kB * kH; i += NTHR)
          sA[(i >> 8) * 260 + (i & 255)] = cload(&o1[i]);
        __syncthreads();
        const int b = tid >> 3, cc = tid & 7;
        float a0 = 0, a1 = 0, a2 = 0, a3 = 0;
        for (int k4 = 0; k4 < 64; ++k4) {
          float4 o4 = sA4[b * 65 + k4];
          float4 w4 = w24[cc * 65 + k4];
          a0 += o4.x * w4.x; a1 += o4.y * w4.y; a2 += o4.z * w4.z; a3 += o4.w * w4.w;
        }
        out[(b * kOut + (s - 1 - kT)) * kC + (bid - 96) * 8 + cc] =
            ((a0 + a1) + (a2 + a3)) + bias2[cc];
      }
      __syncthreads();
    } else if (bid == 128) {
      if (enc) {  // dg2 + gumbel argmax + event scatter
        for (int i = tid; i < kB * kD; i += NTHR) {
          int b = i >> 5, j = i & 31;
          float sv = bdg2s[j];
          for (int k = 0; k < kD; ++k) sv += cload(&l1[b * kD + k]) * w2[k * kD + j];
          lg[b][j] = sv + g[(s * kB + b) * kD + j];
        }
        __syncthreads();
        if (tid < kB) {
          float best = lg[tid][0]; int bi = 0;
          for (int j = 1; j < kD; ++j) { float v = lg[tid][j]; if (v > best) { best = v; bi = j; } }
          sel[tid] = bi;
        }
        __syncthreads();
        for (int i = tid; i < kB * kI; i += NTHR) {
          int b = i >> 6, ii = i & 63;
          int d = sel[b];
          int c = s + 1 + d;
          int e = -1;
          if (c < kT) e = c;
          else { int rr = c - kT - 1;
                 if (rr >= 0 && (rr & 1) == 0) { int kk = rr >> 1; if (kk < kOut) e = kT + kk; } }
          if (e >= 0) {
            float* p = &mem[(b * kSteps + e) * kI + ii];
            cstore(p, cload(p) + x[(b * kT + s) * kI + ii] * dec_s[d]);
          }
        }
      }
    }
    gridbar_nf(baru, nr, grp); nr++;
  }
}

extern "C" void kernel_launch(void* const* d_in, const int* in_sizes, int n_in,
                              void* d_out, int out_size, void* d_ws, size_t ws_size,
                              hipStream_t stream) {
  (void)in_sizes; (void)n_in; (void)out_size; (void)ws_size;
  const float* x      = (const float*)d_in[0];
  const int*   lens   = (const int*)  d_in[1];
  const float* W_dg1  = (const float*)d_in[3];
  const float* b_dg1  = (const float*)d_in[4];
  const float* W_dg2  = (const float*)d_in[5];
  const float* b_dg2  = (const float*)d_in[6];
  const float* W_e1   = (const float*)d_in[7];
  const float* b_e1   = (const float*)d_in[8];
  const float* W_e2   = (const float*)d_in[9];
  const float* b_e2   = (const float*)d_in[10];
  const float* W_ih   = (const float*)d_in[11];
  const float* b_ih   = (const float*)d_in[12];
  const float* W_hh   = (const float*)d_in[13];
  const float* b_hh   = (const float*)d_in[14];
  const float* W_f1   = (const float*)d_in[15];
  const float* b_f1   = (const float*)d_in[16];
  const float* W_f2   = (const float*)d_in[17];
  const float* b_f2   = (const float*)d_in[18];

  hipMemsetAsync(d_ws, 0, WS_ZERO_BYTES, stream);
  delay_rnn<<<dim3(NB), dim3(NTHR), 0, stream>>>(
      x, lens, W_dg1, b_dg1, W_dg2, b_dg2, W_e1, b_e1, W_e2, b_e2,
      W_ih, b_ih, W_hh, b_hh, W_f1, b_f1, W_f2, b_f2,
      (float*)d_out, (float*)d_ws);
}

// Round 6
// 3433.475 us; speedup vs baseline: 1.4081x; 1.2198x over previous
//
#include <hip/hip_runtime.h>
#include <math.h>

// ---------------------------------------------------------------------------
// DelayRNN persistent kernel, R6: ONE grid barrier per step (163 total vs 322).
//  - gh fused into GRU blocks (own-column W_hh slices in LDS) — gh phase and
//    its 24K-float/step L3 round trip deleted.
//  - e1 pipelined: E1 at P(s) computes pre-elu lin_{s+1}; d=0 gate events go
//    through a parity-buffered correction in e1-space (computed by DG block);
//    GRU adds corr + elu while staging. d>=1 events write slots >= s+2.
//  - DG (dg1+dg2+argmax+scatter+corr) fully inside one block.
//  - decoder head pipelined f1@P(s) -> f2@P(s+1), o1/h parity-buffered.
//  - staging via batched global_load_dwordx4 sc0 sc1 (coherent 16B, 1 wait).
//  - 89 blocks: 32 GRU | 32 E1 | 16 F1 | 8 F2 | 1 DG.
// ---------------------------------------------------------------------------

#define kB 32
#define kT 128
#define kI 64
#define kH 256
#define kD 32
#define kC 64
#define kOut 32
#define kSteps (kT + kOut)            // 160
#define NB 89
#define NTHR 256
#define NT_ALL (NB * NTHR)            // 22784
#define BPG 12
#define NGRP 8

// ws float offsets. Zeroed region: [0, WS_NZ)
#define WS_H     384                   // h[2][32][256]
#define WS_CORR  (WS_H + 2*8192)       // corr[2][32][256]
#define WS_MEM   (WS_CORR + 2*8192)    // mem events [32][160][64]
#define WS_NZ    (WS_MEM + kB*kSteps*kI)
#define WS_LIN   WS_NZ                 // lin[2][32][256] (pre-elu e1 out)
#define WS_O1    (WS_LIN + 2*8192)     // o1[2][32][256]
#define WS_W2    (WS_O1 + 2*8192)      // W2 = W_e2@W_ih [256][768]
#define WS_B2    (WS_W2 + kH*3*kH)     // B2 [768]
#define WS_G     (WS_B2 + 3*kH)        // gumbel [T*B*D]
#define WS_ZERO_BYTES ((size_t)WS_NZ * sizeof(float))

// ---- coherent scalar access (agent scope, L3 coherence point) ----
__device__ __forceinline__ float cload(const float* p) {
  return __hip_atomic_load(p, __ATOMIC_RELAXED, __HIP_MEMORY_SCOPE_AGENT);
}
__device__ __forceinline__ void cstore(float* p, float v) {
  __hip_atomic_store(p, v, __ATOMIC_RELAXED, __HIP_MEMORY_SCOPE_AGENT);
}
// coherent 16B load; caller MUST waitvm() before consuming.
__device__ __forceinline__ float4 cload4(const float* p) {
  float4 r;
  asm volatile("global_load_dwordx4 %0, %1, off sc0 sc1" : "=v"(r) : "v"(p));
  return r;
}
__device__ __forceinline__ void waitvm() {
  asm volatile("s_waitcnt vmcnt(0)" ::: "memory");
}

// ---- Threefry-2x32 (jax partitionable path) ----
__device__ __forceinline__ void tf2x32(unsigned k0, unsigned k1,
                                       unsigned x0, unsigned x1,
                                       unsigned& o0, unsigned& o1) {
  unsigned ks2 = k0 ^ k1 ^ 0x1BD11BDAu;
  unsigned v0 = x0 + k0, v1 = x1 + k1;
#define TFR(r) { v0 += v1; v1 = (v1 << (r)) | (v1 >> (32-(r))); v1 ^= v0; }
  TFR(13) TFR(15) TFR(26) TFR(6)   v0 += k1;  v1 += ks2 + 1u;
  TFR(17) TFR(29) TFR(16) TFR(24)  v0 += ks2; v1 += k0  + 2u;
  TFR(13) TFR(15) TFR(26) TFR(6)   v0 += k0;  v1 += k1  + 3u;
  TFR(17) TFR(29) TFR(16) TFR(24)  v0 += k1;  v1 += ks2 + 4u;
  TFR(13) TFR(15) TFR(26) TFR(6)   v0 += ks2; v1 += k0  + 5u;
#undef TFR
  o0 = v0; o1 = v1;
}
__device__ __forceinline__ float bits_to_gumbel(unsigned bits) {
  float f = __uint_as_float((bits >> 9) | 0x3F800000u) - 1.0f;
  float u = f + 1.17549435e-38f;
  return -logf(-logf(u));
}

// Fence-ful flat barrier: used ONCE after init (flushes init/memset L2 lines).
__device__ __forceinline__ void gridbar_full(unsigned* u, unsigned target) {
  __syncthreads();
  if (threadIdx.x == 0) {
    __threadfence();
    __hip_atomic_fetch_add(&u[320], 1u, __ATOMIC_ACQ_REL, __HIP_MEMORY_SCOPE_AGENT);
    while (__hip_atomic_load(&u[320], __ATOMIC_RELAXED, __HIP_MEMORY_SCOPE_AGENT) < target)
      __builtin_amdgcn_s_sleep(1);
    __threadfence();
  }
  __syncthreads();
}
// Fence-free tree barrier (R5): group ctrs -> root -> epoch flag poll.
__device__ __forceinline__ void gridbar_nf(unsigned* u, unsigned nround,
                                           int grp, int gsz) {
  asm volatile("s_waitcnt vmcnt(0) lgkmcnt(0)" ::: "memory");
  __syncthreads();
  if (threadIdx.x == 0) {
    unsigned old = __hip_atomic_fetch_add(&u[grp * 32], 1u,
                      __ATOMIC_RELAXED, __HIP_MEMORY_SCOPE_AGENT);
    if (old + 1u == (unsigned)gsz * nround) {
      unsigned r = __hip_atomic_fetch_add(&u[256], 1u,
                      __ATOMIC_RELAXED, __HIP_MEMORY_SCOPE_AGENT);
      if (r + 1u == NGRP * nround)
        __hip_atomic_store(&u[288], nround, __ATOMIC_RELAXED, __HIP_MEMORY_SCOPE_AGENT);
    }
    while (__hip_atomic_load(&u[288], __ATOMIC_RELAXED, __HIP_MEMORY_SCOPE_AGENT) < nround)
      __builtin_amdgcn_s_sleep(2);
    asm volatile("" ::: "memory");
  }
  __syncthreads();
}

__device__ __forceinline__ float elu1(float v) { return v > 0.f ? v : expm1f(v); }

__global__ __launch_bounds__(NTHR)
void delay_rnn(const float* __restrict__ x, const int* __restrict__ lengths,
               const float* __restrict__ W_dg1, const float* __restrict__ b_dg1,
               const float* __restrict__ W_dg2, const float* __restrict__ b_dg2,
               const float* __restrict__ W_e1,  const float* __restrict__ b_e1,
               const float* __restrict__ W_e2,  const float* __restrict__ b_e2,
               const float* __restrict__ W_ih,  const float* __restrict__ b_ih,
               const float* __restrict__ W_hh,  const float* __restrict__ b_hh,
               const float* __restrict__ W_f1,  const float* __restrict__ b_f1,
               const float* __restrict__ W_f2,  const float* __restrict__ b_f2,
               float* __restrict__ out, float* __restrict__ ws) {
  const int tid = threadIdx.x;
  const int bid = blockIdx.x;
  const int gid = bid * NTHR + tid;
  const int grp = bid / BPG;
  const int gsz = (grp == NGRP - 1) ? (NB - (NGRP - 1) * BPG) : BPG;

  unsigned* baru = (unsigned*)ws;
  float* hBuf  = ws + WS_H;
  float* corrB = ws + WS_CORR;
  float* mem   = ws + WS_MEM;
  float* linB  = ws + WS_LIN;
  float* o1B   = ws + WS_O1;
  float* W2g   = ws + WS_W2;
  float* B2g   = ws + WS_B2;
  float* g     = ws + WS_G;

  __shared__ float S[29120];           // role-carved (max: GRU 29120 floats)
  __shared__ float lgarr[1056];
  __shared__ float sb1[32], sb2[32], dec_sh[32];
  __shared__ int   sel[32], len_s[32];

  // ---------------- init: gumbel, W2 = W_e2@W_ih, B2 ----------------
  {
    unsigned k0, k1;
    tf2x32(0u, 42u, 0u, 0u, k0, k1);
    for (int i = gid; i < kT * kB * kD; i += NT_ALL) {
      unsigned a, b;
      tf2x32(k0, k1, 0u, (unsigned)i, a, b);
      g[i] = bits_to_gumbel(a ^ b);
    }
  }
  for (int idx = gid; idx < kH * 3 * kH; idx += NT_ALL) {
    int k = idx / (3 * kH), n = idx % (3 * kH);
    const float* wr = W_e2 + k * kH;
    float s0 = 0, s1 = 0, s2 = 0, s3 = 0;
    for (int m = 0; m < kH; m += 4) {
      float4 wv = *(const float4*)(wr + m);
      s0 += wv.x * W_ih[(m    ) * 3 * kH + n];
      s1 += wv.y * W_ih[(m + 1) * 3 * kH + n];
      s2 += wv.z * W_ih[(m + 2) * 3 * kH + n];
      s3 += wv.w * W_ih[(m + 3) * 3 * kH + n];
    }
    W2g[idx] = ((s0 + s1) + (s2 + s3));
  }
  for (int n = gid; n < 3 * kH; n += NT_ALL) {
    float s = b_ih[n];
    for (int m = 0; m < kH; ++m) s += b_e2[m] * W_ih[m * 3 * kH + n];
    B2g[n] = s;
  }

  gridbar_full(baru, NB);

  // ---------------- persistent LDS weight staging ----------------
  if (bid < 32) {                                   // GRU: W_hh + W2 slices
    float* whh = S; float* w2 = S + 6240;
    const int jb = bid * 8;
    for (int i = tid; i < 6144; i += NTHR) {
      int gg = i >> 11, r = i & 2047, jj = r >> 8, k = r & 255;
      whh[(gg * 8 + jj) * 260 + k] = W_hh[k * 768 + gg * 256 + jb + jj];
      w2 [(gg * 8 + jj) * 260 + k] = W2g [k * 768 + gg * 256 + jb + jj];
    }
    if (tid < 24) { int gg = tid / 8, jj = tid % 8;
      sb1[tid] = b_hh[gg * 256 + jb + jj];
      sb2[tid] = B2g [gg * 256 + jb + jj];
    }
    if (tid < 32) len_s[tid] = lengths[tid];
  } else if (bid < 64) {                            // E1 + lin_0
    float* we1 = S;
    const int jb = (bid - 32) * 8;
    for (int i = tid; i < 1024; i += NTHR) {
      int jj = i >> 7, k = i & 127;
      we1[jj * 132 + k] = W_e1[k * 256 + jb + jj];
    }
    if (tid < 8) sb1[tid] = b_e1[jb + tid];
    __syncthreads();
    { int b = tid >> 3, jj = tid & 7;               // lin_0 = x_0@We1[:64]+b
      const float* xr = x + (b * kT) * kI;
      float a0 = 0, a1 = 0, a2 = 0, a3 = 0;
      for (int k = 0; k < 64; k += 4) {
        float4 xv = *(const float4*)(xr + k);
        a0 += xv.x * we1[jj * 132 + k];
        a1 += xv.y * we1[jj * 132 + k + 1];
        a2 += xv.z * we1[jj * 132 + k + 2];
        a3 += xv.w * we1[jj * 132 + k + 3];
      }
      cstore(&linB[b * 256 + jb + jj], ((a0 + a1) + (a2 + a3)) + sb1[jj]);
    }
  } else if (bid < 80) {                            // F1
    float* wf1 = S;
    const int jb = (bid - 64) * 16;
    for (int i = tid; i < 4096; i += NTHR) {
      int jj = i >> 8, k = i & 255;
      wf1[jj * 260 + k] = W_f1[k * 256 + jb + jj];
    }
    if (tid < 16) sb1[tid] = b_f1[jb + tid];
  } else if (bid < 88) {                            // F2
    float* wf2 = S;
    const int cb = (bid - 80) * 8;
    for (int i = tid; i < 2048; i += NTHR) {
      int cc = i >> 8, k = i & 255;
      wf2[cc * 260 + k] = W_f2[k * 64 + cb + cc];
    }
    if (tid < 8) sb2[tid] = b_f2[cb + tid];
  } else {                                          // DG
    float* wdg1 = S; float* wdg2 = S + 10368;
    for (int i = tid; i < 10240; i += NTHR) {
      int j = i / 320, k = i % 320;
      wdg1[j * 324 + k] = W_dg1[k * 32 + j];
    }
    for (int i = tid; i < 1024; i += NTHR) wdg2[i] = W_dg2[i];
    if (tid < 32) { sb1[tid] = b_dg1[tid]; sb2[tid] = b_dg2[tid];
                    dec_sh[tid] = powf(0.99f, (float)(tid + 1)); }
  }

  unsigned nr = 1;
  gridbar_nf(baru, nr, grp, gsz); nr++;

  // ---------------- time loop: ONE barrier per phase ----------------
  for (int s = 0; s <= kSteps + 1; ++s) {
    if (bid < 32) {
      // ===== GRU (+inline gh) for step s =====
      if (s < kSteps) {
        float* whh = S; float* w2 = S + 6240;
        float* sH = S + 12480; float* sLin = S + 20800;
        const float* hR = hBuf + (s & 1) * 8192;
        const float* lR = linB + (s & 1) * 8192;
        const float* cR = corrB + (s & 1) * 8192;
        float4 th[8], tl[8], tc[8];
        #pragma unroll
        for (int u8 = 0; u8 < 8; ++u8) {
          int i4 = (tid + u8 * 256) * 4;
          th[u8] = cload4(hR + i4);
          tl[u8] = cload4(lR + i4);
        }
        if (s < kT) {
          #pragma unroll
          for (int u8 = 0; u8 < 8; ++u8) tc[u8] = cload4(cR + (tid + u8 * 256) * 4);
        } else {
          #pragma unroll
          for (int u8 = 0; u8 < 8; ++u8) tc[u8] = make_float4(0.f, 0.f, 0.f, 0.f);
        }
        waitvm();
        #pragma unroll
        for (int u8 = 0; u8 < 8; ++u8) {
          int idx = tid + u8 * 256; int b = idx >> 6, k4 = idx & 63;
          *(float4*)&sH[b * 260 + k4 * 4] = th[u8];
          float4 v;
          v.x = elu1(tl[u8].x + tc[u8].x);
          v.y = elu1(tl[u8].y + tc[u8].y);
          v.z = elu1(tl[u8].z + tc[u8].z);
          v.w = elu1(tl[u8].w + tc[u8].w);
          *(float4*)&sLin[b * 260 + k4 * 4] = v;
        }
        __syncthreads();
        const float4* sH4 = (const float4*)sH;
        const float4* sL4 = (const float4*)sLin;
        const float4* wh4 = (const float4*)whh;
        const float4* w24 = (const float4*)w2;
        const int b = tid >> 3, jj = tid & 7, jg = bid * 8 + jj;
        float gr0=0,gr1=0,gz0=0,gz1=0,gn0=0,gn1=0;
        float ir0=0,ir1=0,iz0=0,iz1=0,in0=0,in1=0;
        for (int k4 = 0; k4 < 64; ++k4) {
          float4 h4 = sH4[b * 65 + k4];
          float4 a4 = sL4[b * 65 + k4];
          float4 w;
          w = wh4[jj * 65 + k4];        gr0 += h4.x*w.x + h4.y*w.y; gr1 += h4.z*w.z + h4.w*w.w;
          w = wh4[(8  + jj) * 65 + k4]; gz0 += h4.x*w.x + h4.y*w.y; gz1 += h4.z*w.z + h4.w*w.w;
          w = wh4[(16 + jj) * 65 + k4]; gn0 += h4.x*w.x + h4.y*w.y; gn1 += h4.z*w.z + h4.w*w.w;
          w = w24[jj * 65 + k4];        ir0 += a4.x*w.x + a4.y*w.y; ir1 += a4.z*w.z + a4.w*w.w;
          w = w24[(8  + jj) * 65 + k4]; iz0 += a4.x*w.x + a4.y*w.y; iz1 += a4.z*w.z + a4.w*w.w;
          w = w24[(16 + jj) * 65 + k4]; in0 += a4.x*w.x + a4.y*w.y; in1 += a4.z*w.z + a4.w*w.w;
        }
        float ghr = (gr0 + gr1) + sb1[jj];
        float ghz = (gz0 + gz1) + sb1[8 + jj];
        float ghn = (gn0 + gn1) + sb1[16 + jj];
        float gir = (ir0 + ir1) + sb2[jj];
        float giz = (iz0 + iz1) + sb2[8 + jj];
        float gin = (in0 + in1) + sb2[16 + jj];
        float r = 1.f / (1.f + expf(-(gir + ghr)));
        float z = 1.f / (1.f + expf(-(giz + ghz)));
        float n = tanhf(gin + r * ghn);
        float hold = sH[b * 260 + jg];
        float nh = (1.f - z) * n + z * hold;
        float hv = (s < kT) ? ((s < len_s[b]) ? nh : hold) : nh;
        cstore(&hBuf[((s + 1) & 1) * 8192 + b * 256 + jg], hv);
      }
    } else if (bid < 64) {
      // ===== E1: lin_{s+1} (pre-elu) =====
      if (s <= kSteps - 2) {
        float* we1 = S; float* sx = S + 1056; float* sm = S + 3232;
        const int jb = (bid - 32) * 8;
        const bool encx = (s + 1 < kT);
        float4 tm[2];
        #pragma unroll
        for (int u2 = 0; u2 < 2; ++u2) {
          int idx = tid + u2 * 256; int b = idx >> 4, k4 = idx & 15;
          tm[u2] = cload4(mem + (b * kSteps + (s + 1)) * kI + k4 * 4);
        }
        waitvm();
        #pragma unroll
        for (int u2 = 0; u2 < 2; ++u2) {
          int idx = tid + u2 * 256; int b = idx >> 4, k4 = idx & 15;
          *(float4*)&sm[b * 68 + k4 * 4] = tm[u2];
          if (encx)
            *(float4*)&sx[b * 68 + k4 * 4] =
                *(const float4*)(x + (b * kT + s + 1) * kI + k4 * 4);
        }
        __syncthreads();
        const int b = tid >> 3, jj = tid & 7;
        const float4* sx4 = (const float4*)sx;
        const float4* sm4 = (const float4*)sm;
        const float4* w4p = (const float4*)we1;
        float a0 = 0, a1 = 0, a2 = 0, a3 = 0;
        if (encx) {
          for (int k4 = 0; k4 < 16; ++k4) {
            float4 xv = sx4[b * 17 + k4], w = w4p[jj * 33 + k4];
            a0 += xv.x * w.x; a1 += xv.y * w.y; a2 += xv.z * w.z; a3 += xv.w * w.w;
          }
        }
        for (int k4 = 0; k4 < 16; ++k4) {
          float4 mv = sm4[b * 17 + k4], w = w4p[jj * 33 + 16 + k4];
          a0 += mv.x * w.x; a1 += mv.y * w.y; a2 += mv.z * w.z; a3 += mv.w * w.w;
        }
        cstore(&linB[((s + 1) & 1) * 8192 + b * 256 + jb + jj],
               ((a0 + a1) + (a2 + a3)) + sb1[jj]);
        __syncthreads();
      }
    } else if (bid < 80) {
      // ===== F1: o1 = relu(h@W_f1+b) for decoder head =====
      if (s >= kT + 1 && s <= kSteps) {
        float* wf1 = S; float* sHf = S + 4160;
        const float* hR = hBuf + (s & 1) * 8192;
        float4 th[8];
        #pragma unroll
        for (int u8 = 0; u8 < 8; ++u8) th[u8] = cload4(hR + (tid + u8 * 256) * 4);
        waitvm();
        #pragma unroll
        for (int u8 = 0; u8 < 8; ++u8) {
          int idx = tid + u8 * 256; int b = idx >> 6, k4 = idx & 63;
          *(float4*)&sHf[b * 260 + k4 * 4] = th[u8];
        }
        __syncthreads();
        const float4* sH4 = (const float4*)sHf;
        const float4* w4p = (const float4*)wf1;
        for (int u2 = 0; u2 < 2; ++u2) {
          int id = tid + u2 * 256; int b = id >> 4, jj = id & 15;
          float a0 = 0, a1 = 0, a2 = 0, a3 = 0;
          for (int k4 = 0; k4 < 64; ++k4) {
            float4 h4 = sH4[b * 65 + k4], w = w4p[jj * 65 + k4];
            a0 += h4.x * w.x; a1 += h4.y * w.y; a2 += h4.z * w.z; a3 += h4.w * w.w;
          }
          float v = ((a0 + a1) + (a2 + a3)) + sb1[jj];
          cstore(&o1B[(s & 1) * 8192 + b * 256 + (bid - 64) * 16 + jj],
                 v > 0.f ? v : 0.f);
        }
        __syncthreads();
      }
    } else if (bid < 88) {
      // ===== F2: out row s-2-kT =====
      if (s >= kT + 2) {
        float* wf2 = S; float* sO = S + 2080;
        const float* oR = o1B + ((s - 1) & 1) * 8192;
        float4 to[8];
        #pragma unroll
        for (int u8 = 0; u8 < 8; ++u8) to[u8] = cload4(oR + (tid + u8 * 256) * 4);
        waitvm();
        #pragma unroll
        for (int u8 = 0; u8 < 8; ++u8) {
          int idx = tid + u8 * 256; int b = idx >> 6, k4 = idx & 63;
          *(float4*)&sO[b * 260 + k4 * 4] = to[u8];
        }
        __syncthreads();
        const float4* sO4 = (const float4*)sO;
        const float4* w4p = (const float4*)wf2;
        const int b = tid >> 3, cc = tid & 7;
        float a0 = 0, a1 = 0, a2 = 0, a3 = 0;
        for (int k4 = 0; k4 < 64; ++k4) {
          float4 o4 = sO4[b * 65 + k4], w = w4p[cc * 65 + k4];
          a0 += o4.x * w.x; a1 += o4.y * w.y; a2 += o4.z * w.z; a3 += o4.w * w.w;
        }
        out[(b * kOut + (s - 2 - kT)) * kC + (bid - 80) * 8 + cc] =
            ((a0 + a1) + (a2 + a3)) + sb2[cc];
        __syncthreads();
      }
    } else {
      // ===== DG: dg1+dg2+argmax+scatter+corr (encoder only) =====
      if (s < kT) {
        float* wdg1 = S; float* wdg2 = S + 10368;
        float* sHd = S + 11392; float* sxd = S + 19712; float* l1s = S + 21888;
        const float* hR = hBuf + (s & 1) * 8192;
        float4 th[8];
        #pragma unroll
        for (int u8 = 0; u8 < 8; ++u8) th[u8] = cload4(hR + (tid + u8 * 256) * 4);
        waitvm();
        #pragma unroll
        for (int u8 = 0; u8 < 8; ++u8) {
          int idx = tid + u8 * 256; int b = idx >> 6, k4 = idx & 63;
          *(float4*)&sHd[b * 260 + k4 * 4] = th[u8];
        }
        #pragma unroll
        for (int u2 = 0; u2 < 2; ++u2) {
          int idx = tid + u2 * 256; int b = idx >> 4, k4 = idx & 15;
          *(float4*)&sxd[b * 68 + k4 * 4] =
              *(const float4*)(x + (b * kT + s) * kI + k4 * 4);
        }
        __syncthreads();
        { // l1 = elu([x_s, h_s]@W_dg1 + b): 4 cols per thread (shared acts)
          const float4* sx4 = (const float4*)sxd;
          const float4* sH4 = (const float4*)sHd;
          const float4* wd4 = (const float4*)wdg1;
          int b = tid >> 3, j0 = (tid & 7) * 4;
          for (int jo = 0; jo < 4; ++jo) {
            int j = j0 + jo;
            float a0 = 0, a1 = 0, a2 = 0, a3 = 0;
            for (int k4 = 0; k4 < 16; ++k4) {
              float4 xv = sx4[b * 17 + k4], w = wd4[j * 81 + k4];
              a0 += xv.x*w.x; a1 += xv.y*w.y; a2 += xv.z*w.z; a3 += xv.w*w.w;
            }
            for (int k4 = 0; k4 < 64; ++k4) {
              float4 h4 = sH4[b * 65 + k4], w = wd4[j * 81 + 16 + k4];
              a0 += h4.x*w.x; a1 += h4.y*w.y; a2 += h4.z*w.z; a3 += h4.w*w.w;
            }
            float v = ((a0 + a1) + (a2 + a3)) + sb1[j];
            l1s[b * 36 + j] = elu1(v);
          }
        }
        __syncthreads();
        for (int it = 0; it < 4; ++it) {          // dg2 + gumbel
          int i = tid + it * 256; int b = i >> 5, j = i & 31;
          float sv = sb2[j];
          for (int k = 0; k < 32; ++k) sv += l1s[b * 36 + k] * wdg2[k * 32 + j];
          lgarr[b * 33 + j] = sv + g[(s * 32 + b) * 32 + j];
        }
        __syncthreads();
        if (tid < 32) {
          float best = lgarr[tid * 33]; int bi = 0;
          for (int j = 1; j < 32; ++j) {
            float v = lgarr[tid * 33 + j];
            if (v > best) { best = v; bi = j; }
          }
          sel[tid] = bi;
        }
        __syncthreads();
        for (int it = 0; it < 8; ++it) {          // mem events, d >= 1
          int i = tid + it * 256; int b = i >> 6, ii = i & 63;
          int d = sel[b];
          if (d > 0) {
            int c = s + 1 + d, e = -1;
            if (c < kT) e = c;
            else { int rr = c - kT - 1;
                   if (rr >= 0 && !(rr & 1)) { int kk = rr >> 1; if (kk < kOut) e = kT + kk; } }
            if (e >= 0) {
              float* p = &mem[(b * kSteps + e) * kI + ii];
              cstore(p, cload(p) + sxd[b * 68 + ii] * dec_sh[d]);
            }
          }
        }
        { // corr (d == 0 event, lands in lin_{s+1} e1-space), parity (s+1)&1
          int j = tid;
          const int p1 = (s + 1) & 1;
          for (int b = 0; b < 32; ++b) {
            float val = 0.f;
            if (sel[b] == 0 && s < kT - 1) {
              float a = 0.f;
              #pragma unroll 8
              for (int k = 0; k < 64; ++k)
                a += sxd[b * 68 + k] * W_e1[(64 + k) * 256 + j];
              val = 0.99f * a;
            }
            cstore(&corrB[p1 * 8192 + b * 256 + j], val);
          }
        }
      }
    }
    gridbar_nf(baru, nr, grp, gsz); nr++;
  }
}

extern "C" void kernel_launch(void* const* d_in, const int* in_sizes, int n_in,
                              void* d_out, int out_size, void* d_ws, size_t ws_size,
                              hipStream_t stream) {
  (void)in_sizes; (void)n_in; (void)out_size; (void)ws_size;
  const float* x      = (const float*)d_in[0];
  const int*   lens   = (const int*)  d_in[1];
  const float* W_dg1  = (const float*)d_in[3];
  const float* b_dg1  = (const float*)d_in[4];
  const float* W_dg2  = (const float*)d_in[5];
  const float* b_dg2  = (const float*)d_in[6];
  const float* W_e1   = (const float*)d_in[7];
  const float* b_e1   = (const float*)d_in[8];
  const float* W_e2   = (const float*)d_in[9];
  const float* b_e2   = (const float*)d_in[10];
  const float* W_ih   = (const float*)d_in[11];
  const float* b_ih   = (const float*)d_in[12];
  const float* W_hh   = (const float*)d_in[13];
  const float* b_hh   = (const float*)d_in[14];
  const float* W_f1   = (const float*)d_in[15];
  const float* b_f1   = (const float*)d_in[16];
  const float* W_f2   = (const float*)d_in[17];
  const float* b_f2   = (const float*)d_in[18];

  hipMemsetAsync(d_ws, 0, WS_ZERO_BYTES, stream);
  delay_rnn<<<dim3(NB), dim3(NTHR), 0, stream>>>(
      x, lens, W_dg1, b_dg1, W_dg2, b_dg2, W_e1, b_e1, W_e2, b_e2,
      W_ih, b_ih, W_hh, b_hh, W_f1, b_f1, W_f2, b_f2,
      (float*)d_out, (float*)d_ws);
}